// Round 1
// baseline (519.392 us; speedup 1.0000x reference)
//
#include <hip/hip_runtime.h>

namespace {

constexpr int E_  = 300;
constexpr int FF_ = 100;
constexpr int AD_ = 64;
constexpr int NH_ = 32;
constexpr int CD_ = 192;   // 3*AD
constexpr int B_  = 16;
constexpr int TQ_ = 32;
constexpr int TD_ = 512;
constexpr int NK_ = 11;

__device__ __forceinline__ float wave_sum(float v) {
#pragma unroll
  for (int o = 32; o > 0; o >>= 1) v += __shfl_down(v, o);
  return v;
}

// block-wide sum over NW waves; result valid in all threads
template <int NW>
__device__ __forceinline__ float blk_sum(float v, float* red) {
  v = wave_sum(v);
  const int lane = threadIdx.x & 63, w = threadIdx.x >> 6;
  __syncthreads();
  if (lane == 0) red[w] = v;
  __syncthreads();
  float s = 0.f;
#pragma unroll
  for (int i = 0; i < NW; ++i) s += red[i];
  return s;
}

// ---------------------------------------------------------------------------
// encode_front: out = x + posenc; h1 = relu(out@W1+b1); ff0 = h1@W2+b2+out;
// ff = LN(ff0)*ffg+ffb; comb = ff@Wc+bc. Also writes normalized raw embedding
// (doc: transposed (B,E,T); query: (B,T,E)). One block (320 thr) per token.
// ---------------------------------------------------------------------------
template <int T, bool DOC>
__global__ __launch_bounds__(320)
void encode_front(const float* __restrict__ x,
                  const float* __restrict__ W1, const float* __restrict__ b1,
                  const float* __restrict__ W2, const float* __restrict__ b2,
                  const float* __restrict__ ffg, const float* __restrict__ ffb,
                  const float* __restrict__ Wc, const float* __restrict__ bc,
                  float* __restrict__ ff_out, float* __restrict__ comb_out,
                  float* __restrict__ xn_out)
{
  __shared__ __align__(16) float s_out[304];
  __shared__ __align__(16) float s_h1[104];
  __shared__ __align__(16) float s_ff[304];
  __shared__ float s_red[8];
  const int bt = blockIdx.x, t = bt % T, b = bt / T;
  const int tid = threadIdx.x;
  const float* xrow = x + (size_t)bt * E_;
  float xv = 0.f, ov = 0.f;
  if (tid < E_) {
    xv = xrow[tid];
    const int f = (tid < 150) ? tid : tid - 150;
    const float inv = __expf(-0.061814365f * (float)f);  // log(1e4)/149
    const float ang = inv * (float)t;
    ov = xv + ((tid < 150) ? sinf(ang) : cosf(ang));
    s_out[tid] = ov;
  }
  const float ssq = blk_sum<5>(xv * xv, s_red);
  if (tid < E_) {
    const float xnv = xv / (sqrtf(ssq) + 1e-13f);
    if (DOC) xn_out[((size_t)b * E_ + tid) * T + t] = xnv;
    else     xn_out[(size_t)bt * E_ + tid] = xnv;
  }
  __syncthreads();
  // h1 = relu(out @ W1 + b1)   (W1 is (300,100), col j coalesced)
  if (tid < FF_) {
    float acc = b1[tid];
    const float* w = W1 + tid;
    for (int i = 0; i < E_; i += 4) {
      const float4 o4 = *(const float4*)&s_out[i];
      acc = fmaf(o4.x, w[(i + 0) * FF_], acc);
      acc = fmaf(o4.y, w[(i + 1) * FF_], acc);
      acc = fmaf(o4.z, w[(i + 2) * FF_], acc);
      acc = fmaf(o4.w, w[(i + 3) * FF_], acc);
    }
    s_h1[tid] = fmaxf(acc, 0.f);
  }
  __syncthreads();
  // ff0 = h1 @ W2 + b2 + out
  float ffv = 0.f;
  if (tid < E_) {
    float acc = b2[tid] + ov;
    const float* w = W2 + tid;
    for (int i = 0; i < FF_; i += 4) {
      const float4 h4 = *(const float4*)&s_h1[i];
      acc = fmaf(h4.x, w[(i + 0) * E_], acc);
      acc = fmaf(h4.y, w[(i + 1) * E_], acc);
      acc = fmaf(h4.z, w[(i + 2) * E_], acc);
      acc = fmaf(h4.w, w[(i + 3) * E_], acc);
    }
    ffv = acc;
  }
  const float sum   = blk_sum<5>((tid < E_) ? ffv : 0.f, s_red);
  const float sumsq = blk_sum<5>((tid < E_) ? ffv * ffv : 0.f, s_red);
  const float mean = sum * (1.f / E_);
  const float var  = fmaxf(sumsq * (1.f / E_) - mean * mean, 0.f);
  const float rstd = 1.f / (sqrtf(var) + 1e-6f);
  if (tid < E_) {
    const float fv = ffg[tid] * (ffv - mean) * rstd + ffb[tid];
    s_ff[tid] = fv;
    ff_out[(size_t)bt * E_ + tid] = fv;
  }
  __syncthreads();
  // comb = ff @ Wc + bc
  if (tid < CD_) {
    float acc = bc[tid];
    const float* w = Wc + tid;
    for (int i = 0; i < E_; i += 4) {
      const float4 f4 = *(const float4*)&s_ff[i];
      acc = fmaf(f4.x, w[(i + 0) * CD_], acc);
      acc = fmaf(f4.y, w[(i + 1) * CD_], acc);
      acc = fmaf(f4.z, w[(i + 2) * CD_], acc);
      acc = fmaf(f4.w, w[(i + 3) * CD_], acc);
    }
    comb_out[(size_t)bt * CD_ + tid] = acc;
  }
}

// ---------------------------------------------------------------------------
// attention: one block per (b,h); thread = query pos. Two-pass softmax.
// p = softmax(sim*m)*m; p /= (sum p + 1e-13). sim*m folded as k*m.
// ---------------------------------------------------------------------------
template <int T>
__global__ __launch_bounds__(512)
void attn(const float* __restrict__ comb, const float* __restrict__ mask,
          float* __restrict__ o)
{
  __shared__ float4 s_kv[T];  // (k0*m, k1*m, v0, v1)
  __shared__ float  s_m[T];
  const int bh = blockIdx.x, b = bh / NH_, h = bh % NH_;
  const int tid = threadIdx.x;
  const float* cb = comb + (size_t)b * T * CD_;
  if (tid < T) {
    const float* c = cb + (size_t)tid * CD_;
    const float m = mask[b * T + tid];
    s_kv[tid] = make_float4(c[AD_ + 2 * h] * m, c[AD_ + 2 * h + 1] * m,
                            c[2 * AD_ + 2 * h], c[2 * AD_ + 2 * h + 1]);
    s_m[tid] = m;
  }
  __syncthreads();
  if (tid < T) {
    const float* c = cb + (size_t)tid * CD_;
    const float q0 = c[2 * h] * (1.f / 3.f);      // scale = sqrt(300//32) = 3
    const float q1 = c[2 * h + 1] * (1.f / 3.f);
    float M = -1e30f;
    for (int j = 0; j < T; ++j) {
      const float4 kv = s_kv[j];
      M = fmaxf(M, fmaf(q0, kv.x, q1 * kv.y));
    }
    float S = 0.f, W = 0.f, a0 = 0.f, a1 = 0.f;
    for (int j = 0; j < T; ++j) {
      const float4 kv = s_kv[j];
      const float s = fmaf(q0, kv.x, q1 * kv.y);
      const float z = __expf(s - M);
      const float w = z * s_m[j];
      S += z; W += w;
      a0 = fmaf(w, kv.z, a0);
      a1 = fmaf(w, kv.w, a1);
    }
    const float dn = 1.f / (W + 1e-13f * S);
    float* op = o + (size_t)(b * T + tid) * AD_ + 2 * h;
    op[0] = a0 * dn;
    op[1] = a1 * dn;
  }
}

// ---------------------------------------------------------------------------
// encode_back: att = o@Wo+bo; ctx = LN(att+ff)*lng+lnb, * mask.
// Doc ctx stored transposed (B,E,T).
// ---------------------------------------------------------------------------
template <int T, bool DOC>
__global__ __launch_bounds__(320)
void encode_back(const float* __restrict__ o, const float* __restrict__ ff,
                 const float* __restrict__ Wo, const float* __restrict__ bo,
                 const float* __restrict__ lng, const float* __restrict__ lnb,
                 const float* __restrict__ mask, float* __restrict__ ctx)
{
  __shared__ __align__(16) float s_o[AD_];
  __shared__ float s_red[8];
  const int bt = blockIdx.x, t = bt % T, b = bt / T;
  const int tid = threadIdx.x;
  if (tid < AD_) s_o[tid] = o[(size_t)bt * AD_ + tid];
  __syncthreads();
  float y = 0.f;
  if (tid < E_) {
    float acc = bo[tid];
    const float* w = Wo + tid;
#pragma unroll
    for (int i = 0; i < AD_; i += 4) {
      const float4 o4 = *(const float4*)&s_o[i];
      acc = fmaf(o4.x, w[(i + 0) * E_], acc);
      acc = fmaf(o4.y, w[(i + 1) * E_], acc);
      acc = fmaf(o4.z, w[(i + 2) * E_], acc);
      acc = fmaf(o4.w, w[(i + 3) * E_], acc);
    }
    y = acc + ff[(size_t)bt * E_ + tid];
  }
  const float sum   = blk_sum<5>((tid < E_) ? y : 0.f, s_red);
  const float sumsq = blk_sum<5>((tid < E_) ? y * y : 0.f, s_red);
  const float mean = sum * (1.f / E_);
  const float var  = fmaxf(sumsq * (1.f / E_) - mean * mean, 0.f);
  const float rstd = 1.f / (sqrtf(var) + 1e-6f);
  const float mk = mask[bt];
  if (tid < E_) {
    const float v = (lng[tid] * (y - mean) * rstd + lnb[tid]) * mk;
    if (DOC) ctx[((size_t)b * E_ + tid) * T + t] = v;
    else     ctx[(size_t)bt * E_ + tid] = v;
  }
}

// ---------------------------------------------------------------------------
// simtanh: cos = qn·dn, dot = qctx·dctx  -> combined (B,2,32,512) = tanh.
// Block: (b, qh in {0,1} -> 16 q rows, dc in {0..3} -> 128 docs). 128 thr.
// ---------------------------------------------------------------------------
__global__ __launch_bounds__(128)
void simtanh(const float* __restrict__ qctx, const float* __restrict__ qn,
             const float* __restrict__ dctxT, const float* __restrict__ dnT,
             float* __restrict__ combined)
{
  __shared__ __align__(16) float s_q[16 * 300];
  __shared__ __align__(16) float s_qn[16 * 300];
  const int bid = blockIdx.x;
  const int dc = bid & 3, qh = (bid >> 2) & 1, b = bid >> 3;
  const int tid = threadIdx.x;
  const float* qc  = qctx + ((size_t)b * 32 + qh * 16) * 300;
  const float* qnp = qn   + ((size_t)b * 32 + qh * 16) * 300;
  for (int idx = tid; idx < 4800; idx += 128) {
    s_q[idx] = qc[idx];
    s_qn[idx] = qnp[idx];
  }
  __syncthreads();
  const int d = dc * 128 + tid;
  const float* dct = dctxT + (size_t)b * 300 * 512 + d;
  const float* dnt = dnT   + (size_t)b * 300 * 512 + d;
  float accD[16], accC[16];
#pragma unroll
  for (int r = 0; r < 16; ++r) { accD[r] = 0.f; accC[r] = 0.f; }
  for (int e = 0; e < 300; e += 4) {
    const float dv0 = dct[(size_t)(e + 0) * 512];
    const float dv1 = dct[(size_t)(e + 1) * 512];
    const float dv2 = dct[(size_t)(e + 2) * 512];
    const float dv3 = dct[(size_t)(e + 3) * 512];
    const float dn0 = dnt[(size_t)(e + 0) * 512];
    const float dn1 = dnt[(size_t)(e + 1) * 512];
    const float dn2 = dnt[(size_t)(e + 2) * 512];
    const float dn3 = dnt[(size_t)(e + 3) * 512];
#pragma unroll
    for (int r = 0; r < 16; ++r) {
      const float4 q4  = *(const float4*)&s_q[r * 300 + e];
      const float4 qn4 = *(const float4*)&s_qn[r * 300 + e];
      float aD = accD[r], aC = accC[r];
      aD = fmaf(q4.x, dv0, aD); aD = fmaf(q4.y, dv1, aD);
      aD = fmaf(q4.z, dv2, aD); aD = fmaf(q4.w, dv3, aD);
      aC = fmaf(qn4.x, dn0, aC); aC = fmaf(qn4.y, dn1, aC);
      aC = fmaf(qn4.z, dn2, aC); aC = fmaf(qn4.w, dn3, aC);
      accD[r] = aD; accC[r] = aC;
    }
  }
  const size_t base = (size_t)b * 2 * 32 * 512;
#pragma unroll
  for (int r = 0; r < 16; ++r) {
    const int qrow = qh * 16 + r;
    combined[base + (size_t)qrow * 512 + d]        = tanhf(accC[r]);  // cos ch
    combined[base + (size_t)(32 + qrow) * 512 + d] = tanhf(accD[r]);  // dot ch
  }
}

// ---------------------------------------------------------------------------
// conv_all: the 5 convs (k=1..5, end-padded) + channel-max -> (B,5,32,512).
// Block per (b, row i); thread = col j.
// ---------------------------------------------------------------------------
template <int K>
__device__ __forceinline__ float conv_max16(const float* __restrict__ s_in, int j,
                                            const float* __restrict__ w,
                                            const float* __restrict__ bias)
{
  float patch[2][K][K];
#pragma unroll
  for (int c = 0; c < 2; ++c)
#pragma unroll
    for (int di = 0; di < K; ++di)
#pragma unroll
      for (int dj = 0; dj < K; ++dj)
        patch[c][di][dj] = s_in[(c * 5 + di) * 516 + j + dj];
  float best = -1e30f;
#pragma unroll
  for (int oc = 0; oc < 16; ++oc) {
    float acc = bias[oc];
#pragma unroll
    for (int c = 0; c < 2; ++c)
#pragma unroll
      for (int di = 0; di < K; ++di)
#pragma unroll
        for (int dj = 0; dj < K; ++dj)
          acc = fmaf(patch[c][di][dj], w[((oc * 2 + c) * K + di) * K + dj], acc);
    best = fmaxf(best, acc);
  }
  return best;
}

__global__ __launch_bounds__(512)
void conv_all(const float* __restrict__ combined,
              const float* __restrict__ c1w, const float* __restrict__ c1b,
              const float* __restrict__ c2w, const float* __restrict__ c2b,
              const float* __restrict__ c3w, const float* __restrict__ c3b,
              const float* __restrict__ c4w, const float* __restrict__ c4b,
              const float* __restrict__ c5w, const float* __restrict__ c5b,
              float* __restrict__ convout)
{
  __shared__ float s_in[2 * 5 * 516];
  __shared__ float s_w[1730];
  __shared__ float s_b[66];
  const int blk = blockIdx.x, b = blk >> 5, i = blk & 31;
  const int tid = threadIdx.x;
  for (int idx = tid; idx < 2 * 5 * 516; idx += 512) {
    const int c = idx / (5 * 516), rem = idx % (5 * 516), r = rem / 516, j = rem % 516;
    const int row = i + r;
    float v = 0.f;
    if (row < 32 && j < 512)
      v = combined[((size_t)(b * 2 + c) * 32 + row) * 512 + j];
    s_in[idx] = v;
  }
  if (tid < 2)   s_w[tid] = c1w[tid];
  if (tid < 128) s_w[2 + tid] = c2w[tid];
  if (tid < 288) s_w[130 + tid] = c3w[tid];
  s_w[418 + tid] = c4w[tid];  // 512 elements
  for (int idx = tid; idx < 800; idx += 512) s_w[930 + idx] = c5w[idx];
  if (tid == 0) s_b[0] = c1b[0];
  if (tid < 16) {
    s_b[1 + tid]  = c2b[tid];
    s_b[17 + tid] = c3b[tid];
    s_b[33 + tid] = c4b[tid];
    s_b[49 + tid] = c5b[tid];
  }
  __syncthreads();
  const int j = tid;
  const float o1 = fmaf(s_in[j], s_w[0], fmaf(s_in[5 * 516 + j], s_w[1], s_b[0]));
  convout[((size_t)(b * 5 + 0) * 32 + i) * 512 + j] = o1;
  convout[((size_t)(b * 5 + 1) * 32 + i) * 512 + j] = conv_max16<2>(s_in, j, s_w + 2,   s_b + 1);
  convout[((size_t)(b * 5 + 2) * 32 + i) * 512 + j] = conv_max16<3>(s_in, j, s_w + 130, s_b + 17);
  convout[((size_t)(b * 5 + 3) * 32 + i) * 512 + j] = conv_max16<4>(s_in, j, s_w + 418, s_b + 33);
  convout[((size_t)(b * 5 + 4) * 32 + i) * 512 + j] = conv_max16<5>(s_in, j, s_w + 930, s_b + 49);
}

// ---------------------------------------------------------------------------
// rbf_pkq: pkq[b,c,q,k] = qm[q] * sum_d exp(-(x-mu_k)^2/(2 sig_k^2)) * dm[d]
// Block per (b,c,q) = 2560 blocks; thread = d.
// ---------------------------------------------------------------------------
__global__ __launch_bounds__(512)
void rbf_pkq(const float* __restrict__ convout, const float* __restrict__ dmask,
             const float* __restrict__ qmask, float* __restrict__ pkq)
{
  __shared__ float red[8][NK_];
  const int id = blockIdx.x;       // (b*5 + c)*32 + q
  const int q = id & 31;
  const int b = id / 160;
  const int tid = threadIdx.x;
  const float x = convout[(size_t)id * 512 + tid];
  const float dmv = dmask[b * 512 + tid];
  const float mu[NK_]  = {1.f, .9f, .7f, .5f, .3f, .1f, -.1f, -.3f, -.5f, -.7f, -.9f};
  const float nis[NK_] = {-5e7f, -50.f, -50.f, -50.f, -50.f, -50.f,
                          -50.f, -50.f, -50.f, -50.f, -50.f};
  const int lane = tid & 63, w = tid >> 6;
#pragma unroll
  for (int k = 0; k < NK_; ++k) {
    const float df = x - mu[k];
    float v = __expf(df * df * nis[k]) * dmv;
    v = wave_sum(v);
    if (lane == 0) red[w][k] = v;
  }
  __syncthreads();
  if (tid < NK_) {
    float s = 0.f;
#pragma unroll
    for (int ww = 0; ww < 8; ++ww) s += red[ww][tid];
    pkq[(size_t)id * NK_ + tid] = s * qmask[b * 32 + q];
  }
}

// ---------------------------------------------------------------------------
// final_k: per_kernel / per_kernel_mean -> dense(55->1) x2 -> dense(2->1).
// ---------------------------------------------------------------------------
__global__ __launch_bounds__(64)
void final_k(const float* __restrict__ pkq, const float* __restrict__ qmask,
             const float* __restrict__ dmask,
             const float* __restrict__ dw, const float* __restrict__ db,
             const float* __restrict__ dmw, const float* __restrict__ dmb,
             const float* __restrict__ cw, float* __restrict__ out)
{
  const int b = blockIdx.x, tid = threadIdx.x;
  float dl = 0.f;
  for (int j = tid; j < 512; j += 64) dl += dmask[b * 512 + j];
  dl = wave_sum(dl);
  dl = __shfl(dl, 0);
  float v1 = 0.f, v2 = 0.f;
  if (tid < 55) {
    const int c = tid / NK_, k = tid % NK_;
    const float rdl = 1.f / dl;
    float s1 = 0.f, s2 = 0.f;
    for (int q = 0; q < 32; ++q) {
      const float p = pkq[(size_t)((b * 5 + c) * 32 + q) * NK_ + k];
      const float qmv = qmask[b * 32 + q];
      s1 += logf(fmaxf(p, 1e-10f)) * qmv;
      s2 += logf(fmaxf(p * rdl, 1e-10f)) * qmv;
    }
    v1 = s1 * dw[tid];
    v2 = s2 * dmw[tid];
  }
  v1 = wave_sum(v1);
  v2 = wave_sum(v2);
  if (tid == 0) out[b] = (v1 + db[0]) * cw[0] + (v2 + dmb[0]) * cw[1];
}

}  // namespace

extern "C" void kernel_launch(void* const* d_in, const int* in_sizes, int n_in,
                              void* d_out, int out_size, void* d_ws, size_t ws_size,
                              hipStream_t stream)
{
  const float* qe  = (const float*)d_in[0];
  const float* de  = (const float*)d_in[1];
  const float* qm  = (const float*)d_in[2];
  const float* dm  = (const float*)d_in[3];
  // d_in[4], d_in[5]: idfs (unused by reference)
  const float* W1  = (const float*)d_in[6];
  const float* b1  = (const float*)d_in[7];
  const float* W2  = (const float*)d_in[8];
  const float* b2  = (const float*)d_in[9];
  const float* ffg = (const float*)d_in[10];
  const float* ffb = (const float*)d_in[11];
  const float* Wc  = (const float*)d_in[12];
  const float* bc  = (const float*)d_in[13];
  const float* Wo  = (const float*)d_in[14];
  const float* bo  = (const float*)d_in[15];
  const float* lng = (const float*)d_in[16];
  const float* lnb = (const float*)d_in[17];
  const float* c1w = (const float*)d_in[18];
  const float* c1b = (const float*)d_in[19];
  const float* c2w = (const float*)d_in[20];
  const float* c2b = (const float*)d_in[21];
  const float* c3w = (const float*)d_in[22];
  const float* c3b = (const float*)d_in[23];
  const float* c4w = (const float*)d_in[24];
  const float* c4b = (const float*)d_in[25];
  const float* c5w = (const float*)d_in[26];
  const float* c5b = (const float*)d_in[27];
  const float* dwp  = (const float*)d_in[28];
  const float* dbp  = (const float*)d_in[29];
  const float* dmwp = (const float*)d_in[30];
  const float* dmbp = (const float*)d_in[31];
  const float* cwp  = (const float*)d_in[32];

  float* ws = (float*)d_ws;
  size_t off = 0;
  auto alloc = [&](size_t n) { float* p = ws + off; off += n; return p; };
  float* ffq      = alloc((size_t)B_ * TQ_ * E_);
  float* combq    = alloc((size_t)B_ * TQ_ * CD_);
  float* oq       = alloc((size_t)B_ * TQ_ * AD_);
  float* qctx     = alloc((size_t)B_ * TQ_ * E_);
  float* qn       = alloc((size_t)B_ * TQ_ * E_);
  float* ffd      = alloc((size_t)B_ * TD_ * E_);
  float* combd    = alloc((size_t)B_ * TD_ * CD_);
  float* od       = alloc((size_t)B_ * TD_ * AD_);
  float* dctxT    = alloc((size_t)B_ * E_ * TD_);
  float* dnT      = alloc((size_t)B_ * E_ * TD_);
  float* combined = alloc((size_t)B_ * 2 * TQ_ * TD_);
  float* convout  = alloc((size_t)B_ * 5 * TQ_ * TD_);
  float* pkq      = alloc((size_t)B_ * 5 * TQ_ * NK_);

  encode_front<TQ_, false><<<B_ * TQ_, 320, 0, stream>>>(
      qe, W1, b1, W2, b2, ffg, ffb, Wc, bc, ffq, combq, qn);
  encode_front<TD_, true><<<B_ * TD_, 320, 0, stream>>>(
      de, W1, b1, W2, b2, ffg, ffb, Wc, bc, ffd, combd, dnT);
  attn<TQ_><<<B_ * NH_, 64, 0, stream>>>(combq, qm, oq);
  attn<TD_><<<B_ * NH_, 512, 0, stream>>>(combd, dm, od);
  encode_back<TQ_, false><<<B_ * TQ_, 320, 0, stream>>>(
      oq, ffq, Wo, bo, lng, lnb, qm, qctx);
  encode_back<TD_, true><<<B_ * TD_, 320, 0, stream>>>(
      od, ffd, Wo, bo, lng, lnb, dm, dctxT);
  simtanh<<<B_ * 8, 128, 0, stream>>>(qctx, qn, dctxT, dnT, combined);
  conv_all<<<B_ * 32, 512, 0, stream>>>(
      combined, c1w, c1b, c2w, c2b, c3w, c3b, c4w, c4b, c5w, c5b, convout);
  rbf_pkq<<<B_ * 5 * TQ_, 512, 0, stream>>>(convout, dm, qm, pkq);
  final_k<<<B_, 64, 0, stream>>>(pkq, qm, dm, dwp, dbp, dmwp, dmbp, cwp,
                                 (float*)d_out);
}

// Round 2
// 446.326 us; speedup vs baseline: 1.1637x; 1.1637x over previous
//
#include <hip/hip_runtime.h>

namespace {

constexpr int E_  = 300;
constexpr int FF_ = 100;
constexpr int AD_ = 64;
constexpr int NH_ = 32;
constexpr int CD_ = 192;   // 3*AD
constexpr int B_  = 16;
constexpr int TQ_ = 32;
constexpr int TD_ = 512;
constexpr int NK_ = 11;
constexpr int DOCBLK_ = 256;   // 8192 doc tokens / 32 per block

__device__ __forceinline__ float wave_sum(float v) {
#pragma unroll
  for (int o = 32; o > 0; o >>= 1) v += __shfl_down(v, o);
  return v;
}

template <int NW>
__device__ __forceinline__ float blk_sum(float v, float* red) {
  v = wave_sum(v);
  const int lane = threadIdx.x & 63, w = threadIdx.x >> 6;
  __syncthreads();
  if (lane == 0) red[w] = v;
  __syncthreads();
  float s = 0.f;
#pragma unroll
  for (int i = 0; i < NW; ++i) s += red[i];
  return s;
}

// swizzled transposed activation slot: [e][t] with XOR on t to spread banks
__device__ __forceinline__ int swz(int e, int t) {
  return e * 32 + (t ^ (((e >> 2) & 7) << 2));
}

__device__ __forceinline__ void fma4(float4& a, float s, const float4& w) {
  a.x = fmaf(s, w.x, a.x); a.y = fmaf(s, w.y, a.y);
  a.z = fmaf(s, w.z, a.z); a.w = fmaf(s, w.w, a.w);
}

// ---------------------------------------------------------------------------
// encode_front_v3: 32 tokens/block, 256 threads, register-tiled fp32 GEMMs.
// Blocks [0,256): doc tokens; [256,272): query tokens.
// Thread (tg=tid>>5, ct=tid&31): owns tokens tg*4..tg*4+3, col-quads by ct.
// ---------------------------------------------------------------------------
__global__ __launch_bounds__(256)
void encode_front_v3(const float* __restrict__ qe, const float* __restrict__ de,
                     const float* __restrict__ W1, const float* __restrict__ b1,
                     const float* __restrict__ W2, const float* __restrict__ b2,
                     const float* __restrict__ ffg, const float* __restrict__ ffb,
                     const float* __restrict__ Wc, const float* __restrict__ bc,
                     float* __restrict__ ffq, float* __restrict__ combq,
                     float* __restrict__ qn,
                     float* __restrict__ ffd, float* __restrict__ combd,
                     float* __restrict__ dnT)
{
  __shared__ float  s_A[9600];    // x / ff transposed+swizzled  [e][t]
  __shared__ float  s_h1[3200];   // h1 transposed+swizzled      [c][t]
  __shared__ float4 s_w4[1500];   // weight chunk buffer (24 KB)
  __shared__ float  s_stat[8][32];
  __shared__ float  s_norm[32];

  const int tid = threadIdx.x;
  const int ct = tid & 31, tg = tid >> 5;
  const int t0 = tg * 4;
  const bool doc = (blockIdx.x < DOCBLK_);
  const int sb = doc ? blockIdx.x : (blockIdx.x - DOCBLK_);
  const float* xs = (doc ? de : qe) + (size_t)sb * 32 * E_;
  float* ffo = doc ? ffd : ffq;
  float* cmo = doc ? combd : combq;
  const size_t tok0 = (size_t)sb * 32;

  // ---- init: raw x -> s_A ----
  for (int i = tid; i < 2400; i += 256) {
    const float4 v = *(const float4*)(xs + (size_t)i * 4);
    const int t = i / 75, e0 = (i % 75) * 4;
    s_A[swz(e0 + 0, t)] = v.x; s_A[swz(e0 + 1, t)] = v.y;
    s_A[swz(e0 + 2, t)] = v.z; s_A[swz(e0 + 3, t)] = v.w;
  }
  __syncthreads();
  { // per-token sumsq of raw x (for xn)
    const int kb = tg * 38, ke = (kb + 38 < 300) ? kb + 38 : 300;
    float ss = 0.f;
    for (int k = kb; k < ke; ++k) { const float v = s_A[swz(k, ct)]; ss = fmaf(v, v, ss); }
    s_stat[tg][ct] = ss;
  }
  __syncthreads();
  if (tid < 32) {
    float s = 0.f;
#pragma unroll
    for (int i = 0; i < 8; ++i) s += s_stat[i][tid];
    s_norm[tid] = 1.f / (sqrtf(s) + 1e-13f);
  }
  __syncthreads();
  // ---- xn write + posenc add (in place) ----
  for (int i = tid; i < 2400; i += 256) {
    const int t = i / 75, e0 = (i % 75) * 4;
    const size_t gt = tok0 + t;
    const int tp = doc ? (int)(gt & 511) : (int)(gt & 31);
    const int b  = doc ? (int)(gt >> 9)  : (int)(gt >> 5);
    const float nm = s_norm[t];
#pragma unroll
    for (int j = 0; j < 4; ++j) {
      const int e = e0 + j;
      const int slot = swz(e, t);
      const float raw = s_A[slot];
      if (doc) dnT[((size_t)b * E_ + e) * 512 + tp] = raw * nm;
      else     qn[gt * E_ + e] = raw * nm;
      const int f = (e < 150) ? e : e - 150;
      const float ang = __expf(-0.061814365f * (float)f) * (float)tp;
      s_A[slot] = raw + ((e < 150) ? sinf(ang) : cosf(ang));
    }
  }
  __syncthreads();

  // ---- phase 1: h1 = relu(out @ W1 + b1), N=100 (25 quads, ct<25) ----
  {
    const int cq = (ct < 25) ? ct : 24;
    float4 a1[4];
#pragma unroll
    for (int r = 0; r < 4; ++r) a1[r] = make_float4(0.f, 0.f, 0.f, 0.f);
    for (int k0 = 0; k0 < 300; k0 += 60) {          // 5 chunks of 60x100
      for (int i = tid; i < 1500; i += 256)
        s_w4[i] = *(const float4*)(W1 + (size_t)k0 * FF_ + (size_t)i * 4);
      __syncthreads();
#pragma unroll 4
      for (int kk = 0; kk < 60; ++kk) {
        const float4 xv = *(const float4*)&s_A[swz(k0 + kk, t0)];
        const float4 w = s_w4[kk * 25 + cq];
        fma4(a1[0], xv.x, w); fma4(a1[1], xv.y, w);
        fma4(a1[2], xv.z, w); fma4(a1[3], xv.w, w);
      }
      __syncthreads();
    }
    if (ct < 25) {
      const float4 bb = *(const float4*)&b1[4 * ct];
#pragma unroll
      for (int r = 0; r < 4; ++r) {
        const int t = t0 + r;
        s_h1[swz(4 * ct + 0, t)] = fmaxf(a1[r].x + bb.x, 0.f);
        s_h1[swz(4 * ct + 1, t)] = fmaxf(a1[r].y + bb.y, 0.f);
        s_h1[swz(4 * ct + 2, t)] = fmaxf(a1[r].z + bb.z, 0.f);
        s_h1[swz(4 * ct + 3, t)] = fmaxf(a1[r].w + bb.w, 0.f);
      }
    }
    __syncthreads();
  }

  // ---- phase 2: ff0 = h1 @ W2 + b2 + out; LN -> ff (into s_A + global) ----
  {
    const int q2 = (ct < 11) ? ct + 64 : 74;
    const bool val2 = (ct < 11);
    float4 a2[3][4];
#pragma unroll
    for (int p = 0; p < 3; ++p)
#pragma unroll
      for (int r = 0; r < 4; ++r) a2[p][r] = make_float4(0.f, 0.f, 0.f, 0.f);
    for (int k0 = 0; k0 < 100; k0 += 20) {          // 5 chunks of 20x300
      for (int i = tid; i < 1500; i += 256)
        s_w4[i] = *(const float4*)(W2 + (size_t)k0 * E_ + (size_t)i * 4);
      __syncthreads();
#pragma unroll 4
      for (int kk = 0; kk < 20; ++kk) {
        const float4 hv = *(const float4*)&s_h1[swz(k0 + kk, t0)];
        const float4 w0 = s_w4[kk * 75 + ct];
        const float4 w1 = s_w4[kk * 75 + ct + 32];
        const float4 w2 = s_w4[kk * 75 + q2];
        fma4(a2[0][0], hv.x, w0); fma4(a2[0][1], hv.y, w0);
        fma4(a2[0][2], hv.z, w0); fma4(a2[0][3], hv.w, w0);
        fma4(a2[1][0], hv.x, w1); fma4(a2[1][1], hv.y, w1);
        fma4(a2[1][2], hv.z, w1); fma4(a2[1][3], hv.w, w1);
        fma4(a2[2][0], hv.x, w2); fma4(a2[2][1], hv.y, w2);
        fma4(a2[2][2], hv.z, w2); fma4(a2[2][3], hv.w, w2);
      }
      __syncthreads();
    }
    const int qs0 = ct, qs1 = ct + 32, qs2 = q2;
    float sum[4] = {0.f, 0.f, 0.f, 0.f}, sq[4] = {0.f, 0.f, 0.f, 0.f};
#pragma unroll
    for (int p = 0; p < 3; ++p) {
      const int qq = (p == 0) ? qs0 : (p == 1) ? qs1 : qs2;
      const float4 bb = *(const float4*)&b2[4 * qq];
      const bool ok = (p < 2) || val2;
#pragma unroll
      for (int r = 0; r < 4; ++r) {
        const int t = t0 + r;
        float4 v = a2[p][r];
        v.x += bb.x + s_A[swz(4 * qq + 0, t)];
        v.y += bb.y + s_A[swz(4 * qq + 1, t)];
        v.z += bb.z + s_A[swz(4 * qq + 2, t)];
        v.w += bb.w + s_A[swz(4 * qq + 3, t)];
        a2[p][r] = v;
        if (ok) {
          sum[r] += v.x + v.y + v.z + v.w;
          sq[r] = fmaf(v.x, v.x, fmaf(v.y, v.y, fmaf(v.z, v.z, fmaf(v.w, v.w, sq[r]))));
        }
      }
    }
#pragma unroll
    for (int m = 1; m <= 16; m <<= 1) {
#pragma unroll
      for (int r = 0; r < 4; ++r) {
        sum[r] += __shfl_xor(sum[r], m);
        sq[r]  += __shfl_xor(sq[r], m);
      }
    }
    float mean[4], rstd[4];
#pragma unroll
    for (int r = 0; r < 4; ++r) {
      mean[r] = sum[r] * (1.f / 300.f);
      const float var = fmaxf(sq[r] * (1.f / 300.f) - mean[r] * mean[r], 0.f);
      rstd[r] = 1.f / (sqrtf(var) + 1e-6f);
    }
    __syncthreads();   // all residual reads of s_A done; now overwrite with ff
#pragma unroll
    for (int p = 0; p < 3; ++p) {
      if (p == 2 && !val2) break;
      const int qq = (p == 0) ? qs0 : (p == 1) ? qs1 : qs2;
      const int c0 = 4 * qq;
      const float4 g4 = *(const float4*)&ffg[c0];
      const float4 b4 = *(const float4*)&ffb[c0];
#pragma unroll
      for (int r = 0; r < 4; ++r) {
        const int t = t0 + r;
        const float4 v = a2[p][r];
        float4 fv;
        fv.x = fmaf(g4.x, (v.x - mean[r]) * rstd[r], b4.x);
        fv.y = fmaf(g4.y, (v.y - mean[r]) * rstd[r], b4.y);
        fv.z = fmaf(g4.z, (v.z - mean[r]) * rstd[r], b4.z);
        fv.w = fmaf(g4.w, (v.w - mean[r]) * rstd[r], b4.w);
        *(float4*)&ffo[(tok0 + t) * E_ + c0] = fv;
        s_A[swz(c0 + 0, t)] = fv.x; s_A[swz(c0 + 1, t)] = fv.y;
        s_A[swz(c0 + 2, t)] = fv.z; s_A[swz(c0 + 3, t)] = fv.w;
      }
    }
    __syncthreads();
  }

  // ---- phase 3: comb = ff @ Wc + bc, N=192 (48 quads) ----
  {
    const int q3 = (ct < 16) ? ct + 32 : 47;
    float4 a3[2][4];
#pragma unroll
    for (int p = 0; p < 2; ++p)
#pragma unroll
      for (int r = 0; r < 4; ++r) a3[p][r] = make_float4(0.f, 0.f, 0.f, 0.f);
    for (int k0 = 0; k0 < 300; k0 += 30) {          // 10 chunks of 30x192
      for (int i = tid; i < 1440; i += 256)
        s_w4[i] = *(const float4*)(Wc + (size_t)k0 * CD_ + (size_t)i * 4);
      __syncthreads();
#pragma unroll 5
      for (int kk = 0; kk < 30; ++kk) {
        const float4 xv = *(const float4*)&s_A[swz(k0 + kk, t0)];
        const float4 w0 = s_w4[kk * 48 + ct];
        const float4 w1 = s_w4[kk * 48 + q3];
        fma4(a3[0][0], xv.x, w0); fma4(a3[0][1], xv.y, w0);
        fma4(a3[0][2], xv.z, w0); fma4(a3[0][3], xv.w, w0);
        fma4(a3[1][0], xv.x, w1); fma4(a3[1][1], xv.y, w1);
        fma4(a3[1][2], xv.z, w1); fma4(a3[1][3], xv.w, w1);
      }
      __syncthreads();
    }
    const float4 bb0 = *(const float4*)&bc[4 * ct];
#pragma unroll
    for (int r = 0; r < 4; ++r) {
      float4 o = a3[0][r];
      o.x += bb0.x; o.y += bb0.y; o.z += bb0.z; o.w += bb0.w;
      *(float4*)&cmo[(tok0 + t0 + r) * CD_ + 4 * ct] = o;
    }
    if (ct < 16) {
      const float4 bb1 = *(const float4*)&bc[4 * (ct + 32)];
#pragma unroll
      for (int r = 0; r < 4; ++r) {
        float4 o = a3[1][r];
        o.x += bb1.x; o.y += bb1.y; o.z += bb1.z; o.w += bb1.w;
        *(float4*)&cmo[(tok0 + t0 + r) * CD_ + 4 * (ct + 32)] = o;
      }
    }
  }
}

// ---------------------------------------------------------------------------
// attention: one block per (b,h); thread = query pos. Two-pass softmax.
// ---------------------------------------------------------------------------
template <int T>
__global__ __launch_bounds__(512)
void attn(const float* __restrict__ comb, const float* __restrict__ mask,
          float* __restrict__ o)
{
  __shared__ float4 s_kv[T];  // (k0*m, k1*m, v0, v1)
  __shared__ float  s_m[T];
  const int bh = blockIdx.x, b = bh / NH_, h = bh % NH_;
  const int tid = threadIdx.x;
  const float* cb = comb + (size_t)b * T * CD_;
  if (tid < T) {
    const float* c = cb + (size_t)tid * CD_;
    const float m = mask[b * T + tid];
    s_kv[tid] = make_float4(c[AD_ + 2 * h] * m, c[AD_ + 2 * h + 1] * m,
                            c[2 * AD_ + 2 * h], c[2 * AD_ + 2 * h + 1]);
    s_m[tid] = m;
  }
  __syncthreads();
  if (tid < T) {
    const float* c = cb + (size_t)tid * CD_;
    const float q0 = c[2 * h] * (1.f / 3.f);
    const float q1 = c[2 * h + 1] * (1.f / 3.f);
    float M = -1e30f;
    for (int j = 0; j < T; ++j) {
      const float4 kv = s_kv[j];
      M = fmaxf(M, fmaf(q0, kv.x, q1 * kv.y));
    }
    float S = 0.f, W = 0.f, a0 = 0.f, a1 = 0.f;
    for (int j = 0; j < T; ++j) {
      const float4 kv = s_kv[j];
      const float s = fmaf(q0, kv.x, q1 * kv.y);
      const float z = __expf(s - M);
      const float w = z * s_m[j];
      S += z; W += w;
      a0 = fmaf(w, kv.z, a0);
      a1 = fmaf(w, kv.w, a1);
    }
    const float dn = 1.f / (W + 1e-13f * S);
    float* op = o + (size_t)(b * T + tid) * AD_ + 2 * h;
    op[0] = a0 * dn;
    op[1] = a1 * dn;
  }
}

// ---------------------------------------------------------------------------
// encode_back: att = o@Wo+bo; ctx = LN(att+ff)*lng+lnb, * mask.
// ---------------------------------------------------------------------------
template <int T, bool DOC>
__global__ __launch_bounds__(320)
void encode_back(const float* __restrict__ o, const float* __restrict__ ff,
                 const float* __restrict__ Wo, const float* __restrict__ bo,
                 const float* __restrict__ lng, const float* __restrict__ lnb,
                 const float* __restrict__ mask, float* __restrict__ ctx)
{
  __shared__ __align__(16) float s_o[AD_];
  __shared__ float s_red[8];
  const int bt = blockIdx.x, t = bt % T, b = bt / T;
  const int tid = threadIdx.x;
  if (tid < AD_) s_o[tid] = o[(size_t)bt * AD_ + tid];
  __syncthreads();
  float y = 0.f;
  if (tid < E_) {
    float acc = bo[tid];
    const float* w = Wo + tid;
#pragma unroll
    for (int i = 0; i < AD_; i += 4) {
      const float4 o4 = *(const float4*)&s_o[i];
      acc = fmaf(o4.x, w[(i + 0) * E_], acc);
      acc = fmaf(o4.y, w[(i + 1) * E_], acc);
      acc = fmaf(o4.z, w[(i + 2) * E_], acc);
      acc = fmaf(o4.w, w[(i + 3) * E_], acc);
    }
    y = acc + ff[(size_t)bt * E_ + tid];
  }
  const float sum   = blk_sum<5>((tid < E_) ? y : 0.f, s_red);
  const float sumsq = blk_sum<5>((tid < E_) ? y * y : 0.f, s_red);
  const float mean = sum * (1.f / E_);
  const float var  = fmaxf(sumsq * (1.f / E_) - mean * mean, 0.f);
  const float rstd = 1.f / (sqrtf(var) + 1e-6f);
  const float mk = mask[bt];
  if (tid < E_) {
    const float v = (lng[tid] * (y - mean) * rstd + lnb[tid]) * mk;
    if (DOC) ctx[((size_t)b * E_ + tid) * T + t] = v;
    else     ctx[(size_t)bt * E_ + tid] = v;
  }
}

// ---------------------------------------------------------------------------
// simtanh: cos = qn·dn, dot = qctx·dctx  -> combined (B,2,32,512) = tanh.
// ---------------------------------------------------------------------------
__global__ __launch_bounds__(128)
void simtanh(const float* __restrict__ qctx, const float* __restrict__ qn,
             const float* __restrict__ dctxT, const float* __restrict__ dnT,
             float* __restrict__ combined)
{
  __shared__ __align__(16) float s_q[16 * 300];
  __shared__ __align__(16) float s_qn[16 * 300];
  const int bid = blockIdx.x;
  const int dc = bid & 3, qh = (bid >> 2) & 1, b = bid >> 3;
  const int tid = threadIdx.x;
  const float* qc  = qctx + ((size_t)b * 32 + qh * 16) * 300;
  const float* qnp = qn   + ((size_t)b * 32 + qh * 16) * 300;
  for (int idx = tid; idx < 4800; idx += 128) {
    s_q[idx] = qc[idx];
    s_qn[idx] = qnp[idx];
  }
  __syncthreads();
  const int d = dc * 128 + tid;
  const float* dct = dctxT + (size_t)b * 300 * 512 + d;
  const float* dnt = dnT   + (size_t)b * 300 * 512 + d;
  float accD[16], accC[16];
#pragma unroll
  for (int r = 0; r < 16; ++r) { accD[r] = 0.f; accC[r] = 0.f; }
  for (int e = 0; e < 300; e += 4) {
    const float dv0 = dct[(size_t)(e + 0) * 512];
    const float dv1 = dct[(size_t)(e + 1) * 512];
    const float dv2 = dct[(size_t)(e + 2) * 512];
    const float dv3 = dct[(size_t)(e + 3) * 512];
    const float dn0 = dnt[(size_t)(e + 0) * 512];
    const float dn1 = dnt[(size_t)(e + 1) * 512];
    const float dn2 = dnt[(size_t)(e + 2) * 512];
    const float dn3 = dnt[(size_t)(e + 3) * 512];
#pragma unroll
    for (int r = 0; r < 16; ++r) {
      const float4 q4  = *(const float4*)&s_q[r * 300 + e];
      const float4 qn4 = *(const float4*)&s_qn[r * 300 + e];
      float aD = accD[r], aC = accC[r];
      aD = fmaf(q4.x, dv0, aD); aD = fmaf(q4.y, dv1, aD);
      aD = fmaf(q4.z, dv2, aD); aD = fmaf(q4.w, dv3, aD);
      aC = fmaf(qn4.x, dn0, aC); aC = fmaf(qn4.y, dn1, aC);
      aC = fmaf(qn4.z, dn2, aC); aC = fmaf(qn4.w, dn3, aC);
      accD[r] = aD; accC[r] = aC;
    }
  }
  const size_t base = (size_t)b * 2 * 32 * 512;
#pragma unroll
  for (int r = 0; r < 16; ++r) {
    const int qrow = qh * 16 + r;
    combined[base + (size_t)qrow * 512 + d]        = tanhf(accC[r]);
    combined[base + (size_t)(32 + qrow) * 512 + d] = tanhf(accD[r]);
  }
}

// ---------------------------------------------------------------------------
// conv_all: 5 convs (k=1..5, end-padded) + channel-max -> (B,5,32,512).
// ---------------------------------------------------------------------------
template <int K>
__device__ __forceinline__ float conv_max16(const float* __restrict__ s_in, int j,
                                            const float* __restrict__ w,
                                            const float* __restrict__ bias)
{
  float patch[2][K][K];
#pragma unroll
  for (int c = 0; c < 2; ++c)
#pragma unroll
    for (int di = 0; di < K; ++di)
#pragma unroll
      for (int dj = 0; dj < K; ++dj)
        patch[c][di][dj] = s_in[(c * 5 + di) * 516 + j + dj];
  float best = -1e30f;
#pragma unroll
  for (int oc = 0; oc < 16; ++oc) {
    float acc = bias[oc];
#pragma unroll
    for (int c = 0; c < 2; ++c)
#pragma unroll
      for (int di = 0; di < K; ++di)
#pragma unroll
        for (int dj = 0; dj < K; ++dj)
          acc = fmaf(patch[c][di][dj], w[((oc * 2 + c) * K + di) * K + dj], acc);
    best = fmaxf(best, acc);
  }
  return best;
}

__global__ __launch_bounds__(512)
void conv_all(const float* __restrict__ combined,
              const float* __restrict__ c1w, const float* __restrict__ c1b,
              const float* __restrict__ c2w, const float* __restrict__ c2b,
              const float* __restrict__ c3w, const float* __restrict__ c3b,
              const float* __restrict__ c4w, const float* __restrict__ c4b,
              const float* __restrict__ c5w, const float* __restrict__ c5b,
              float* __restrict__ convout)
{
  __shared__ float s_in[2 * 5 * 516];
  __shared__ float s_w[1730];
  __shared__ float s_b[66];
  const int blk = blockIdx.x, b = blk >> 5, i = blk & 31;
  const int tid = threadIdx.x;
  for (int idx = tid; idx < 2 * 5 * 516; idx += 512) {
    const int c = idx / (5 * 516), rem = idx % (5 * 516), r = rem / 516, j = rem % 516;
    const int row = i + r;
    float v = 0.f;
    if (row < 32 && j < 512)
      v = combined[((size_t)(b * 2 + c) * 32 + row) * 512 + j];
    s_in[idx] = v;
  }
  if (tid < 2)   s_w[tid] = c1w[tid];
  if (tid < 128) s_w[2 + tid] = c2w[tid];
  if (tid < 288) s_w[130 + tid] = c3w[tid];
  s_w[418 + tid] = c4w[tid];
  for (int idx = tid; idx < 800; idx += 512) s_w[930 + idx] = c5w[idx];
  if (tid == 0) s_b[0] = c1b[0];
  if (tid < 16) {
    s_b[1 + tid]  = c2b[tid];
    s_b[17 + tid] = c3b[tid];
    s_b[33 + tid] = c4b[tid];
    s_b[49 + tid] = c5b[tid];
  }
  __syncthreads();
  const int j = tid;
  const float o1 = fmaf(s_in[j], s_w[0], fmaf(s_in[5 * 516 + j], s_w[1], s_b[0]));
  convout[((size_t)(b * 5 + 0) * 32 + i) * 512 + j] = o1;
  convout[((size_t)(b * 5 + 1) * 32 + i) * 512 + j] = conv_max16<2>(s_in, j, s_w + 2,   s_b + 1);
  convout[((size_t)(b * 5 + 2) * 32 + i) * 512 + j] = conv_max16<3>(s_in, j, s_w + 130, s_b + 17);
  convout[((size_t)(b * 5 + 3) * 32 + i) * 512 + j] = conv_max16<4>(s_in, j, s_w + 418, s_b + 33);
  convout[((size_t)(b * 5 + 4) * 32 + i) * 512 + j] = conv_max16<5>(s_in, j, s_w + 930, s_b + 49);
}

// ---------------------------------------------------------------------------
// rbf_pkq
// ---------------------------------------------------------------------------
__global__ __launch_bounds__(512)
void rbf_pkq(const float* __restrict__ convout, const float* __restrict__ dmask,
             const float* __restrict__ qmask, float* __restrict__ pkq)
{
  __shared__ float red[8][NK_];
  const int id = blockIdx.x;
  const int q = id & 31;
  const int b = id / 160;
  const int tid = threadIdx.x;
  const float x = convout[(size_t)id * 512 + tid];
  const float dmv = dmask[b * 512 + tid];
  const float mu[NK_]  = {1.f, .9f, .7f, .5f, .3f, .1f, -.1f, -.3f, -.5f, -.7f, -.9f};
  const float nis[NK_] = {-5e7f, -50.f, -50.f, -50.f, -50.f, -50.f,
                          -50.f, -50.f, -50.f, -50.f, -50.f};
  const int lane = tid & 63, w = tid >> 6;
#pragma unroll
  for (int k = 0; k < NK_; ++k) {
    const float df = x - mu[k];
    float v = __expf(df * df * nis[k]) * dmv;
    v = wave_sum(v);
    if (lane == 0) red[w][k] = v;
  }
  __syncthreads();
  if (tid < NK_) {
    float s = 0.f;
#pragma unroll
    for (int ww = 0; ww < 8; ++ww) s += red[ww][tid];
    pkq[(size_t)id * NK_ + tid] = s * qmask[b * 32 + q];
  }
}

// ---------------------------------------------------------------------------
// final_k
// ---------------------------------------------------------------------------
__global__ __launch_bounds__(64)
void final_k(const float* __restrict__ pkq, const float* __restrict__ qmask,
             const float* __restrict__ dmask,
             const float* __restrict__ dw, const float* __restrict__ db,
             const float* __restrict__ dmw, const float* __restrict__ dmb,
             const float* __restrict__ cw, float* __restrict__ out)
{
  const int b = blockIdx.x, tid = threadIdx.x;
  float dl = 0.f;
  for (int j = tid; j < 512; j += 64) dl += dmask[b * 512 + j];
  dl = wave_sum(dl);
  dl = __shfl(dl, 0);
  float v1 = 0.f, v2 = 0.f;
  if (tid < 55) {
    const int c = tid / NK_, k = tid % NK_;
    const float rdl = 1.f / dl;
    float s1 = 0.f, s2 = 0.f;
    for (int q = 0; q < 32; ++q) {
      const float p = pkq[(size_t)((b * 5 + c) * 32 + q) * NK_ + k];
      const float qmv = qmask[b * 32 + q];
      s1 += logf(fmaxf(p, 1e-10f)) * qmv;
      s2 += logf(fmaxf(p * rdl, 1e-10f)) * qmv;
    }
    v1 = s1 * dw[tid];
    v2 = s2 * dmw[tid];
  }
  v1 = wave_sum(v1);
  v2 = wave_sum(v2);
  if (tid == 0) out[b] = (v1 + db[0]) * cw[0] + (v2 + dmb[0]) * cw[1];
}

}  // namespace

extern "C" void kernel_launch(void* const* d_in, const int* in_sizes, int n_in,
                              void* d_out, int out_size, void* d_ws, size_t ws_size,
                              hipStream_t stream)
{
  const float* qe  = (const float*)d_in[0];
  const float* de  = (const float*)d_in[1];
  const float* qm  = (const float*)d_in[2];
  const float* dm  = (const float*)d_in[3];
  const float* W1  = (const float*)d_in[6];
  const float* b1  = (const float*)d_in[7];
  const float* W2  = (const float*)d_in[8];
  const float* b2  = (const float*)d_in[9];
  const float* ffg = (const float*)d_in[10];
  const float* ffb = (const float*)d_in[11];
  const float* Wc  = (const float*)d_in[12];
  const float* bc  = (const float*)d_in[13];
  const float* Wo  = (const float*)d_in[14];
  const float* bo  = (const float*)d_in[15];
  const float* lng = (const float*)d_in[16];
  const float* lnb = (const float*)d_in[17];
  const float* c1w = (const float*)d_in[18];
  const float* c1b = (const float*)d_in[19];
  const float* c2w = (const float*)d_in[20];
  const float* c2b = (const float*)d_in[21];
  const float* c3w = (const float*)d_in[22];
  const float* c3b = (const float*)d_in[23];
  const float* c4w = (const float*)d_in[24];
  const float* c4b = (const float*)d_in[25];
  const float* c5w = (const float*)d_in[26];
  const float* c5b = (const float*)d_in[27];
  const float* dwp  = (const float*)d_in[28];
  const float* dbp  = (const float*)d_in[29];
  const float* dmwp = (const float*)d_in[30];
  const float* dmbp = (const float*)d_in[31];
  const float* cwp  = (const float*)d_in[32];

  float* ws = (float*)d_ws;
  size_t off = 0;
  auto alloc = [&](size_t n) { float* p = ws + off; off += n; return p; };
  float* ffq      = alloc((size_t)B_ * TQ_ * E_);
  float* combq    = alloc((size_t)B_ * TQ_ * CD_);
  float* oq       = alloc((size_t)B_ * TQ_ * AD_);
  float* qctx     = alloc((size_t)B_ * TQ_ * E_);
  float* qn       = alloc((size_t)B_ * TQ_ * E_);
  float* ffd      = alloc((size_t)B_ * TD_ * E_);
  float* combd    = alloc((size_t)B_ * TD_ * CD_);
  float* od       = alloc((size_t)B_ * TD_ * AD_);
  float* dctxT    = alloc((size_t)B_ * E_ * TD_);
  float* dnT      = alloc((size_t)B_ * E_ * TD_);
  float* combined = alloc((size_t)B_ * 2 * TQ_ * TD_);
  float* convout  = alloc((size_t)B_ * 5 * TQ_ * TD_);
  float* pkq      = alloc((size_t)B_ * 5 * TQ_ * NK_);

  encode_front_v3<<<DOCBLK_ + 16, 256, 0, stream>>>(
      qe, de, W1, b1, W2, b2, ffg, ffb, Wc, bc,
      ffq, combq, qn, ffd, combd, dnT);
  attn<TQ_><<<B_ * NH_, 64, 0, stream>>>(combq, qm, oq);
  attn<TD_><<<B_ * NH_, 512, 0, stream>>>(combd, dm, od);
  encode_back<TQ_, false><<<B_ * TQ_, 320, 0, stream>>>(
      oq, ffq, Wo, bo, lng, lnb, qm, qctx);
  encode_back<TD_, true><<<B_ * TD_, 320, 0, stream>>>(
      od, ffd, Wo, bo, lng, lnb, dm, dctxT);
  simtanh<<<B_ * 8, 128, 0, stream>>>(qctx, qn, dctxT, dnT, combined);
  conv_all<<<B_ * 32, 512, 0, stream>>>(
      combined, c1w, c1b, c2w, c2b, c3w, c3b, c4w, c4b, c5w, c5b, convout);
  rbf_pkq<<<B_ * 5 * TQ_, 512, 0, stream>>>(convout, dm, qm, pkq);
  final_k<<<B_, 64, 0, stream>>>(pkq, qm, dm, dwp, dbp, dmwp, dmbp, cwp,
                                 (float*)d_out);
}

// Round 3
// 377.246 us; speedup vs baseline: 1.3768x; 1.1831x over previous
//
#include <hip/hip_runtime.h>

namespace {

constexpr int E_  = 300;
constexpr int FF_ = 100;
constexpr int AD_ = 64;
constexpr int NH_ = 32;
constexpr int CD_ = 192;   // 3*AD
constexpr int B_  = 16;
constexpr int TQ_ = 32;
constexpr int TD_ = 512;
constexpr int NK_ = 11;
constexpr int DOCBLK_ = 512;   // 8192 doc tokens / 16 per block

__device__ __forceinline__ float wave_sum(float v) {
#pragma unroll
  for (int o = 32; o > 0; o >>= 1) v += __shfl_down(v, o);
  return v;
}

// swizzled transposed activation slot: [e][t], t in 0..15; XOR on bits>=1 so
// even token pairs stay contiguous (b64 reads), banks spread for col reads.
__device__ __forceinline__ int swz16(int e, int t) {
  return e * 16 + (t ^ (((e >> 2) & 7) << 1));
}

__device__ __forceinline__ void fma4(float4& a, float s, const float4& w) {
  a.x = fmaf(s, w.x, a.x); a.y = fmaf(s, w.y, a.y);
  a.z = fmaf(s, w.z, a.z); a.w = fmaf(s, w.w, a.w);
}

// ---------------------------------------------------------------------------
// encode_front_v4: 16 tokens/block, 256 threads (tg=tid>>5 owns 2 tokens,
// ct=tid&31 owns column quads). Blocks [0,512): doc; [512,544): query.
// ~51 KB LDS -> 2-3 blocks/CU resident.
// ---------------------------------------------------------------------------
__global__ __launch_bounds__(256)
void encode_front_v4(const float* __restrict__ qe, const float* __restrict__ de,
                     const float* __restrict__ W1, const float* __restrict__ b1,
                     const float* __restrict__ W2, const float* __restrict__ b2,
                     const float* __restrict__ ffg, const float* __restrict__ ffb,
                     const float* __restrict__ Wc, const float* __restrict__ bc,
                     float* __restrict__ ffq, float* __restrict__ combq,
                     float* __restrict__ qn,
                     float* __restrict__ ffd, float* __restrict__ combd,
                     float* __restrict__ dnT)
{
  __shared__ float  s_A[4800];    // x / ff transposed+swizzled [e][16]
  __shared__ float  s_h1[1600];   // h1 transposed+swizzled     [c][16]
  __shared__ float4 s_w4[1500];   // weight chunk buffer (24 KB)
  __shared__ float  s_stat[16][17];
  __shared__ float  s_norm[16];

  const int tid = threadIdx.x;
  const int ct = tid & 31, tg = tid >> 5;
  const int t0 = tg * 2;
  const bool doc = (blockIdx.x < DOCBLK_);
  const int sb = doc ? blockIdx.x : (blockIdx.x - DOCBLK_);
  const float* xs = (doc ? de : qe) + (size_t)sb * 16 * E_;
  float* ffo = doc ? ffd : ffq;
  float* cmo = doc ? combd : combq;
  const size_t tok0 = (size_t)sb * 16;
  const int bb_ = doc ? (int)(tok0 >> 9) : (int)(tok0 >> 5);
  const int tp0 = doc ? (int)(tok0 & 511) : (int)(tok0 & 31);

  // ---- init: raw x -> s_A ----
  for (int i = tid; i < 1200; i += 256) {
    const float4 v = *(const float4*)(xs + (size_t)i * 4);
    const int t = i / 75, e0 = (i % 75) * 4;
    s_A[swz16(e0 + 0, t)] = v.x; s_A[swz16(e0 + 1, t)] = v.y;
    s_A[swz16(e0 + 2, t)] = v.z; s_A[swz16(e0 + 3, t)] = v.w;
  }
  __syncthreads();
  { // per-token sumsq of raw x (for xn): 16 chunks x 16 tokens
    const int tk = tid & 15, ch = tid >> 4;
    const int kb = ch * 19, ke = (kb + 19 < 300) ? kb + 19 : 300;
    float ss = 0.f;
    for (int k = kb; k < ke; ++k) { const float v = s_A[swz16(k, tk)]; ss = fmaf(v, v, ss); }
    s_stat[ch][tk] = ss;
  }
  __syncthreads();
  if (tid < 16) {
    float s = 0.f;
#pragma unroll
    for (int i = 0; i < 16; ++i) s += s_stat[i][tid];
    s_norm[tid] = 1.f / (sqrtf(s) + 1e-13f);
  }
  __syncthreads();
  // ---- xn write + posenc add (in place) ----
  for (int i = tid; i < 1200; i += 256) {
    const int t = i / 75, e0 = (i % 75) * 4;
    const int tp = tp0 + t;
    const float nm = s_norm[t];
#pragma unroll
    for (int j = 0; j < 4; ++j) {
      const int e = e0 + j;
      const int slot = swz16(e, t);
      const float raw = s_A[slot];
      if (doc) dnT[((size_t)bb_ * E_ + e) * 512 + tp] = raw * nm;
      else     qn[(tok0 + t) * E_ + e] = raw * nm;
      const int f = (e < 150) ? e : e - 150;
      const float ang = __expf(-0.061814365f * (float)f) * (float)tp;
      s_A[slot] = raw + ((e < 150) ? sinf(ang) : cosf(ang));
    }
  }
  __syncthreads();

  // ---- phase 1: h1 = relu(out @ W1 + b1), N=100 (25 quads, ct<25) ----
  {
    const int cq = (ct < 25) ? ct : 24;
    float4 a1[2];
    a1[0] = make_float4(0.f, 0.f, 0.f, 0.f);
    a1[1] = make_float4(0.f, 0.f, 0.f, 0.f);
    for (int k0 = 0; k0 < 300; k0 += 60) {          // 5 chunks of 60x100
      for (int i = tid; i < 1500; i += 256)
        s_w4[i] = *(const float4*)(W1 + (size_t)k0 * FF_ + (size_t)i * 4);
      __syncthreads();
#pragma unroll 6
      for (int kk = 0; kk < 60; ++kk) {
        const float2 xv = *(const float2*)&s_A[swz16(k0 + kk, t0)];
        const float4 w = s_w4[kk * 25 + cq];
        fma4(a1[0], xv.x, w); fma4(a1[1], xv.y, w);
      }
      __syncthreads();
    }
    if (ct < 25) {
      const float4 bb = *(const float4*)&b1[4 * ct];
#pragma unroll
      for (int r = 0; r < 2; ++r) {
        const int t = t0 + r;
        const float4 a = (r == 0) ? a1[0] : a1[1];
        s_h1[swz16(4 * ct + 0, t)] = fmaxf(a.x + bb.x, 0.f);
        s_h1[swz16(4 * ct + 1, t)] = fmaxf(a.y + bb.y, 0.f);
        s_h1[swz16(4 * ct + 2, t)] = fmaxf(a.z + bb.z, 0.f);
        s_h1[swz16(4 * ct + 3, t)] = fmaxf(a.w + bb.w, 0.f);
      }
    }
    __syncthreads();
  }

  // ---- phase 2: ff0 = h1 @ W2 + b2 + out; LN -> ff (into s_A + global) ----
  {
    const int q2 = (ct < 11) ? ct + 64 : 74;
    const bool val2 = (ct < 11);
    float4 a2[3][2];
#pragma unroll
    for (int p = 0; p < 3; ++p)
#pragma unroll
      for (int r = 0; r < 2; ++r) a2[p][r] = make_float4(0.f, 0.f, 0.f, 0.f);
    for (int k0 = 0; k0 < 100; k0 += 20) {          // 5 chunks of 20x300
      for (int i = tid; i < 1500; i += 256)
        s_w4[i] = *(const float4*)(W2 + (size_t)k0 * E_ + (size_t)i * 4);
      __syncthreads();
#pragma unroll 5
      for (int kk = 0; kk < 20; ++kk) {
        const float2 hv = *(const float2*)&s_h1[swz16(k0 + kk, t0)];
        const float4 w0 = s_w4[kk * 75 + ct];
        const float4 w1 = s_w4[kk * 75 + ct + 32];
        const float4 w2 = s_w4[kk * 75 + q2];
        fma4(a2[0][0], hv.x, w0); fma4(a2[0][1], hv.y, w0);
        fma4(a2[1][0], hv.x, w1); fma4(a2[1][1], hv.y, w1);
        fma4(a2[2][0], hv.x, w2); fma4(a2[2][1], hv.y, w2);
      }
      __syncthreads();
    }
    float sum[2] = {0.f, 0.f}, sq[2] = {0.f, 0.f};
#pragma unroll
    for (int p = 0; p < 3; ++p) {
      const int qq = (p == 0) ? ct : (p == 1) ? ct + 32 : q2;
      const float4 bb = *(const float4*)&b2[4 * qq];
      const bool ok = (p < 2) || val2;
#pragma unroll
      for (int r = 0; r < 2; ++r) {
        const int t = t0 + r;
        float4 v = a2[p][r];
        v.x += bb.x + s_A[swz16(4 * qq + 0, t)];
        v.y += bb.y + s_A[swz16(4 * qq + 1, t)];
        v.z += bb.z + s_A[swz16(4 * qq + 2, t)];
        v.w += bb.w + s_A[swz16(4 * qq + 3, t)];
        a2[p][r] = v;
        if (ok) {
          sum[r] += v.x + v.y + v.z + v.w;
          sq[r] = fmaf(v.x, v.x, fmaf(v.y, v.y, fmaf(v.z, v.z, fmaf(v.w, v.w, sq[r]))));
        }
      }
    }
#pragma unroll
    for (int m = 1; m <= 16; m <<= 1) {
#pragma unroll
      for (int r = 0; r < 2; ++r) {
        sum[r] += __shfl_xor(sum[r], m);
        sq[r]  += __shfl_xor(sq[r], m);
      }
    }
    float mean[2], rstd[2];
#pragma unroll
    for (int r = 0; r < 2; ++r) {
      mean[r] = sum[r] * (1.f / 300.f);
      const float var = fmaxf(sq[r] * (1.f / 300.f) - mean[r] * mean[r], 0.f);
      rstd[r] = 1.f / (sqrtf(var) + 1e-6f);
    }
    __syncthreads();   // all residual reads of s_A done; now overwrite with ff
#pragma unroll
    for (int p = 0; p < 3; ++p) {
      if (p == 2 && !val2) break;
      const int qq = (p == 0) ? ct : (p == 1) ? ct + 32 : q2;
      const int c0 = 4 * qq;
      const float4 g4 = *(const float4*)&ffg[c0];
      const float4 b4 = *(const float4*)&ffb[c0];
#pragma unroll
      for (int r = 0; r < 2; ++r) {
        const int t = t0 + r;
        const float4 v = a2[p][r];
        float4 fv;
        fv.x = fmaf(g4.x, (v.x - mean[r]) * rstd[r], b4.x);
        fv.y = fmaf(g4.y, (v.y - mean[r]) * rstd[r], b4.y);
        fv.z = fmaf(g4.z, (v.z - mean[r]) * rstd[r], b4.z);
        fv.w = fmaf(g4.w, (v.w - mean[r]) * rstd[r], b4.w);
        *(float4*)&ffo[(tok0 + t) * E_ + c0] = fv;
        s_A[swz16(c0 + 0, t)] = fv.x; s_A[swz16(c0 + 1, t)] = fv.y;
        s_A[swz16(c0 + 2, t)] = fv.z; s_A[swz16(c0 + 3, t)] = fv.w;
      }
    }
    __syncthreads();
  }

  // ---- phase 3: comb = ff @ Wc + bc, N=192 (48 quads) ----
  {
    const int q3 = (ct < 16) ? ct + 32 : 47;
    float4 a3[2][2];
#pragma unroll
    for (int p = 0; p < 2; ++p)
#pragma unroll
      for (int r = 0; r < 2; ++r) a3[p][r] = make_float4(0.f, 0.f, 0.f, 0.f);
    for (int k0 = 0; k0 < 300; k0 += 30) {          // 10 chunks of 30x192
      for (int i = tid; i < 1440; i += 256)
        s_w4[i] = *(const float4*)(Wc + (size_t)k0 * CD_ + (size_t)i * 4);
      __syncthreads();
#pragma unroll 6
      for (int kk = 0; kk < 30; ++kk) {
        const float2 xv = *(const float2*)&s_A[swz16(k0 + kk, t0)];
        const float4 w0 = s_w4[kk * 48 + ct];
        const float4 w1 = s_w4[kk * 48 + q3];
        fma4(a3[0][0], xv.x, w0); fma4(a3[0][1], xv.y, w0);
        fma4(a3[1][0], xv.x, w1); fma4(a3[1][1], xv.y, w1);
      }
      __syncthreads();
    }
    const float4 bb0 = *(const float4*)&bc[4 * ct];
#pragma unroll
    for (int r = 0; r < 2; ++r) {
      float4 o = a3[0][r];
      o.x += bb0.x; o.y += bb0.y; o.z += bb0.z; o.w += bb0.w;
      *(float4*)&cmo[(tok0 + t0 + r) * CD_ + 4 * ct] = o;
    }
    if (ct < 16) {
      const float4 bb1 = *(const float4*)&bc[4 * (ct + 32)];
#pragma unroll
      for (int r = 0; r < 2; ++r) {
        float4 o = a3[1][r];
        o.x += bb1.x; o.y += bb1.y; o.z += bb1.z; o.w += bb1.w;
        *(float4*)&cmo[(tok0 + t0 + r) * CD_ + 4 * (ct + 32)] = o;
      }
    }
  }
}

// ---------------------------------------------------------------------------
// attention: one block per (b,h); thread = query pos. Two-pass softmax.
// ---------------------------------------------------------------------------
template <int T>
__global__ __launch_bounds__(512)
void attn(const float* __restrict__ comb, const float* __restrict__ mask,
          float* __restrict__ o)
{
  __shared__ float4 s_kv[T];  // (k0*m, k1*m, v0, v1)
  __shared__ float  s_m[T];
  const int bh = blockIdx.x, b = bh / NH_, h = bh % NH_;
  const int tid = threadIdx.x;
  const float* cb = comb + (size_t)b * T * CD_;
  if (tid < T) {
    const float* c = cb + (size_t)tid * CD_;
    const float m = mask[b * T + tid];
    s_kv[tid] = make_float4(c[AD_ + 2 * h] * m, c[AD_ + 2 * h + 1] * m,
                            c[2 * AD_ + 2 * h], c[2 * AD_ + 2 * h + 1]);
    s_m[tid] = m;
  }
  __syncthreads();
  if (tid < T) {
    const float* c = cb + (size_t)tid * CD_;
    const float q0 = c[2 * h] * (1.f / 3.f);
    const float q1 = c[2 * h + 1] * (1.f / 3.f);
    float M = -1e30f;
    for (int j = 0; j < T; ++j) {
      const float4 kv = s_kv[j];
      M = fmaxf(M, fmaf(q0, kv.x, q1 * kv.y));
    }
    float S = 0.f, W = 0.f, a0 = 0.f, a1 = 0.f;
    for (int j = 0; j < T; ++j) {
      const float4 kv = s_kv[j];
      const float s = fmaf(q0, kv.x, q1 * kv.y);
      const float z = __expf(s - M);
      const float w = z * s_m[j];
      S += z; W += w;
      a0 = fmaf(w, kv.z, a0);
      a1 = fmaf(w, kv.w, a1);
    }
    const float dn = 1.f / (W + 1e-13f * S);
    float* op = o + (size_t)(b * T + tid) * AD_ + 2 * h;
    op[0] = a0 * dn;
    op[1] = a1 * dn;
  }
}

// ---------------------------------------------------------------------------
// encode_back_v2: merged doc+query. 16 tokens/block, 256 threads, same tiling
// as encode_front_v4. att = o@Wo+bo; ctx = LN(att+ff)*lng+lnb, * mask.
// ---------------------------------------------------------------------------
__global__ __launch_bounds__(256)
void encode_back_v2(const float* __restrict__ oq, const float* __restrict__ od,
                    const float* __restrict__ ffq, const float* __restrict__ ffd,
                    const float* __restrict__ Wo, const float* __restrict__ bo,
                    const float* __restrict__ lng, const float* __restrict__ lnb,
                    const float* __restrict__ qm, const float* __restrict__ dm,
                    float* __restrict__ qctx, float* __restrict__ dctxT)
{
  __shared__ float  s_O[1024];    // o transposed+swizzled [c][16]
  __shared__ float4 s_w4[1200];   // Wo chunk (19.2 KB)

  const int tid = threadIdx.x;
  const int ct = tid & 31, tg = tid >> 5;
  const int t0 = tg * 2;
  const bool doc = (blockIdx.x < DOCBLK_);
  const int sb = doc ? blockIdx.x : (blockIdx.x - DOCBLK_);
  const size_t tok0 = (size_t)sb * 16;
  const float* op = doc ? od : oq;
  const float* ffp = doc ? ffd : ffq;
  const float* mp = doc ? dm : qm;
  const int bb_ = doc ? (int)(tok0 >> 9) : 0;
  const int tp0 = doc ? (int)(tok0 & 511) : 0;

  { // load o (16x64) transposed into s_O
    const int i = tid;  // exactly 256 float4
    const int t = i >> 4, c0 = (i & 15) * 4;
    const float4 v = *(const float4*)(op + (tok0 + t) * AD_ + c0);
    s_O[swz16(c0 + 0, t)] = v.x; s_O[swz16(c0 + 1, t)] = v.y;
    s_O[swz16(c0 + 2, t)] = v.z; s_O[swz16(c0 + 3, t)] = v.w;
  }
  __syncthreads();

  const int q2 = (ct < 11) ? ct + 64 : 74;
  const bool val2 = (ct < 11);
  float4 a[3][2];
#pragma unroll
  for (int p = 0; p < 3; ++p)
#pragma unroll
    for (int r = 0; r < 2; ++r) a[p][r] = make_float4(0.f, 0.f, 0.f, 0.f);
  for (int k0 = 0; k0 < 64; k0 += 16) {             // 4 chunks of 16x300
    for (int i = tid; i < 1200; i += 256)
      s_w4[i] = *(const float4*)(Wo + (size_t)k0 * E_ + (size_t)i * 4);
    __syncthreads();
#pragma unroll 4
    for (int kk = 0; kk < 16; ++kk) {
      const float2 ov = *(const float2*)&s_O[swz16(k0 + kk, t0)];
      const float4 w0 = s_w4[kk * 75 + ct];
      const float4 w1 = s_w4[kk * 75 + ct + 32];
      const float4 w2 = s_w4[kk * 75 + q2];
      fma4(a[0][0], ov.x, w0); fma4(a[0][1], ov.y, w0);
      fma4(a[1][0], ov.x, w1); fma4(a[1][1], ov.y, w1);
      fma4(a[2][0], ov.x, w2); fma4(a[2][1], ov.y, w2);
    }
    __syncthreads();
  }
  // residual + LN stats
  float sum[2] = {0.f, 0.f}, sq[2] = {0.f, 0.f};
#pragma unroll
  for (int p = 0; p < 3; ++p) {
    const int qq = (p == 0) ? ct : (p == 1) ? ct + 32 : q2;
    const float4 bb = *(const float4*)&bo[4 * qq];
    const bool ok = (p < 2) || val2;
#pragma unroll
    for (int r = 0; r < 2; ++r) {
      const int t = t0 + r;
      const float4 f4 = *(const float4*)(ffp + (tok0 + t) * E_ + 4 * qq);
      float4 v = a[p][r];
      v.x += bb.x + f4.x; v.y += bb.y + f4.y;
      v.z += bb.z + f4.z; v.w += bb.w + f4.w;
      a[p][r] = v;
      if (ok) {
        sum[r] += v.x + v.y + v.z + v.w;
        sq[r] = fmaf(v.x, v.x, fmaf(v.y, v.y, fmaf(v.z, v.z, fmaf(v.w, v.w, sq[r]))));
      }
    }
  }
#pragma unroll
  for (int m = 1; m <= 16; m <<= 1) {
#pragma unroll
    for (int r = 0; r < 2; ++r) {
      sum[r] += __shfl_xor(sum[r], m);
      sq[r]  += __shfl_xor(sq[r], m);
    }
  }
#pragma unroll
  for (int r = 0; r < 2; ++r) {
    const int t = t0 + r;
    const float mean = sum[r] * (1.f / 300.f);
    const float var  = fmaxf(sq[r] * (1.f / 300.f) - mean * mean, 0.f);
    const float rstd = 1.f / (sqrtf(var) + 1e-6f);
    const float mk = mp[tok0 + t];
#pragma unroll
    for (int p = 0; p < 3; ++p) {
      if (p == 2 && !val2) break;
      const int qq = (p == 0) ? ct : (p == 1) ? ct + 32 : q2;
      const int c0 = 4 * qq;
      const float4 g4 = *(const float4*)&lng[c0];
      const float4 b4 = *(const float4*)&lnb[c0];
      const float4 v = a[p][r];
      float4 fv;
      fv.x = fmaf(g4.x, (v.x - mean) * rstd, b4.x) * mk;
      fv.y = fmaf(g4.y, (v.y - mean) * rstd, b4.y) * mk;
      fv.z = fmaf(g4.z, (v.z - mean) * rstd, b4.z) * mk;
      fv.w = fmaf(g4.w, (v.w - mean) * rstd, b4.w) * mk;
      if (doc) {
        const int tp = tp0 + t;
        dctxT[((size_t)bb_ * E_ + c0 + 0) * 512 + tp] = fv.x;
        dctxT[((size_t)bb_ * E_ + c0 + 1) * 512 + tp] = fv.y;
        dctxT[((size_t)bb_ * E_ + c0 + 2) * 512 + tp] = fv.z;
        dctxT[((size_t)bb_ * E_ + c0 + 3) * 512 + tp] = fv.w;
      } else {
        *(float4*)&qctx[(tok0 + t) * E_ + c0] = fv;
      }
    }
  }
}

// ---------------------------------------------------------------------------
// simtanh_v2: 256 blocks (b,qh,dc: 16x2x8) x 512 threads (epart=wave 0..7,
// dlane 0..63). Each thread: partial dots over ~40 e for 16 q x 2 types x 1 d.
// LDS reduce across eparts, then tanh + coalesced store.
// ---------------------------------------------------------------------------
__global__ __launch_bounds__(512)
void simtanh_v2(const float* __restrict__ qctx, const float* __restrict__ qn,
                const float* __restrict__ dctxT, const float* __restrict__ dnT,
                float* __restrict__ combined)
{
  __shared__ float s_q[2 * 16 * 304];     // [type][q][e]
  __shared__ float s_part[8 * 32 * 64];   // [epart][q*2+type][dlane]

  const int bid = blockIdx.x;
  const int sub = bid & 15, b = bid >> 4;
  const int qh = sub >> 3, dc = sub & 7;
  const int tid = threadIdx.x;
  const int ep = tid >> 6, dlane = tid & 63;
  const int d = dc * 64 + dlane;

  const float* qc  = qctx + ((size_t)b * 32 + qh * 16) * E_;
  const float* qnp = qn   + ((size_t)b * 32 + qh * 16) * E_;
  for (int i = tid; i < 1200; i += 512) {
    const int q = i / 75, e0 = (i % 75) * 4;
    *(float4*)&s_q[(0 * 16 + q) * 304 + e0] = *(const float4*)(qc + q * E_ + e0);
    *(float4*)&s_q[(1 * 16 + q) * 304 + e0] = *(const float4*)(qnp + q * E_ + e0);
  }
  __syncthreads();

  const float* dct = dctxT + (size_t)b * E_ * 512 + d;
  const float* dnt = dnT   + (size_t)b * E_ * 512 + d;
  float accD[16], accC[16];
#pragma unroll
  for (int q = 0; q < 16; ++q) { accD[q] = 0.f; accC[q] = 0.f; }
  const int es = ep * 40, ee = (es + 40 < 300) ? es + 40 : 300;
  for (int e0 = es; e0 < ee; e0 += 4) {
    const float dv0 = dct[(size_t)(e0 + 0) * 512];
    const float dv1 = dct[(size_t)(e0 + 1) * 512];
    const float dv2 = dct[(size_t)(e0 + 2) * 512];
    const float dv3 = dct[(size_t)(e0 + 3) * 512];
    const float dn0 = dnt[(size_t)(e0 + 0) * 512];
    const float dn1 = dnt[(size_t)(e0 + 1) * 512];
    const float dn2 = dnt[(size_t)(e0 + 2) * 512];
    const float dn3 = dnt[(size_t)(e0 + 3) * 512];
#pragma unroll
    for (int q = 0; q < 16; ++q) {
      const float4 qd = *(const float4*)&s_q[(0 * 16 + q) * 304 + e0];
      const float4 qc4 = *(const float4*)&s_q[(1 * 16 + q) * 304 + e0];
      float aD = accD[q], aC = accC[q];
      aD = fmaf(qd.x, dv0, aD); aD = fmaf(qd.y, dv1, aD);
      aD = fmaf(qd.z, dv2, aD); aD = fmaf(qd.w, dv3, aD);
      aC = fmaf(qc4.x, dn0, aC); aC = fmaf(qc4.y, dn1, aC);
      aC = fmaf(qc4.z, dn2, aC); aC = fmaf(qc4.w, dn3, aC);
      accD[q] = aD; accC[q] = aC;
    }
  }
#pragma unroll
  for (int q = 0; q < 16; ++q) {
    s_part[(ep * 32 + q * 2 + 0) * 64 + dlane] = accC[q];  // cos
    s_part[(ep * 32 + q * 2 + 1) * 64 + dlane] = accD[q];  // dot
  }
  __syncthreads();
  // final: each thread handles 4 slots for its dlane
  const int s0 = (tid >> 6) * 4;
#pragma unroll
  for (int si = 0; si < 4; ++si) {
    const int s = s0 + si;
    float v = 0.f;
#pragma unroll
    for (int p = 0; p < 8; ++p) v += s_part[(p * 32 + s) * 64 + dlane];
    const int q = s >> 1, typ = s & 1;
    combined[(((size_t)b * 2 + typ) * 32 + qh * 16 + q) * 512 + d] = tanhf(v);
  }
}

// ---------------------------------------------------------------------------
// conv_all: 5 convs (k=1..5, end-padded) + channel-max -> (B,5,32,512).
// ---------------------------------------------------------------------------
template <int K>
__device__ __forceinline__ float conv_max16(const float* __restrict__ s_in, int j,
                                            const float* __restrict__ w,
                                            const float* __restrict__ bias)
{
  float patch[2][K][K];
#pragma unroll
  for (int c = 0; c < 2; ++c)
#pragma unroll
    for (int di = 0; di < K; ++di)
#pragma unroll
      for (int dj = 0; dj < K; ++dj)
        patch[c][di][dj] = s_in[(c * 5 + di) * 516 + j + dj];
  float best = -1e30f;
#pragma unroll
  for (int oc = 0; oc < 16; ++oc) {
    float acc = bias[oc];
#pragma unroll
    for (int c = 0; c < 2; ++c)
#pragma unroll
      for (int di = 0; di < K; ++di)
#pragma unroll
        for (int dj = 0; dj < K; ++dj)
          acc = fmaf(patch[c][di][dj], w[((oc * 2 + c) * K + di) * K + dj], acc);
    best = fmaxf(best, acc);
  }
  return best;
}

__global__ __launch_bounds__(512)
void conv_all(const float* __restrict__ combined,
              const float* __restrict__ c1w, const float* __restrict__ c1b,
              const float* __restrict__ c2w, const float* __restrict__ c2b,
              const float* __restrict__ c3w, const float* __restrict__ c3b,
              const float* __restrict__ c4w, const float* __restrict__ c4b,
              const float* __restrict__ c5w, const float* __restrict__ c5b,
              float* __restrict__ convout)
{
  __shared__ float s_in[2 * 5 * 516];
  __shared__ float s_w[1730];
  __shared__ float s_b[66];
  const int blk = blockIdx.x, b = blk >> 5, i = blk & 31;
  const int tid = threadIdx.x;
  for (int idx = tid; idx < 2 * 5 * 516; idx += 512) {
    const int c = idx / (5 * 516), rem = idx % (5 * 516), r = rem / 516, j = rem % 516;
    const int row = i + r;
    float v = 0.f;
    if (row < 32 && j < 512)
      v = combined[((size_t)(b * 2 + c) * 32 + row) * 512 + j];
    s_in[idx] = v;
  }
  if (tid < 2)   s_w[tid] = c1w[tid];
  if (tid < 128) s_w[2 + tid] = c2w[tid];
  if (tid < 288) s_w[130 + tid] = c3w[tid];
  s_w[418 + tid] = c4w[tid];
  for (int idx = tid; idx < 800; idx += 512) s_w[930 + idx] = c5w[idx];
  if (tid == 0) s_b[0] = c1b[0];
  if (tid < 16) {
    s_b[1 + tid]  = c2b[tid];
    s_b[17 + tid] = c3b[tid];
    s_b[33 + tid] = c4b[tid];
    s_b[49 + tid] = c5b[tid];
  }
  __syncthreads();
  const int j = tid;
  const float o1 = fmaf(s_in[j], s_w[0], fmaf(s_in[5 * 516 + j], s_w[1], s_b[0]));
  convout[((size_t)(b * 5 + 0) * 32 + i) * 512 + j] = o1;
  convout[((size_t)(b * 5 + 1) * 32 + i) * 512 + j] = conv_max16<2>(s_in, j, s_w + 2,   s_b + 1);
  convout[((size_t)(b * 5 + 2) * 32 + i) * 512 + j] = conv_max16<3>(s_in, j, s_w + 130, s_b + 17);
  convout[((size_t)(b * 5 + 3) * 32 + i) * 512 + j] = conv_max16<4>(s_in, j, s_w + 418, s_b + 33);
  convout[((size_t)(b * 5 + 4) * 32 + i) * 512 + j] = conv_max16<5>(s_in, j, s_w + 930, s_b + 49);
}

// ---------------------------------------------------------------------------
// rbf_pkq
// ---------------------------------------------------------------------------
__global__ __launch_bounds__(512)
void rbf_pkq(const float* __restrict__ convout, const float* __restrict__ dmask,
             const float* __restrict__ qmask, float* __restrict__ pkq)
{
  __shared__ float red[8][NK_];
  const int id = blockIdx.x;
  const int q = id & 31;
  const int b = id / 160;
  const int tid = threadIdx.x;
  const float x = convout[(size_t)id * 512 + tid];
  const float dmv = dmask[b * 512 + tid];
  const float mu[NK_]  = {1.f, .9f, .7f, .5f, .3f, .1f, -.1f, -.3f, -.5f, -.7f, -.9f};
  const float nis[NK_] = {-5e7f, -50.f, -50.f, -50.f, -50.f, -50.f,
                          -50.f, -50.f, -50.f, -50.f, -50.f};
  const int lane = tid & 63, w = tid >> 6;
#pragma unroll
  for (int k = 0; k < NK_; ++k) {
    const float df = x - mu[k];
    float v = __expf(df * df * nis[k]) * dmv;
    v = wave_sum(v);
    if (lane == 0) red[w][k] = v;
  }
  __syncthreads();
  if (tid < NK_) {
    float s = 0.f;
#pragma unroll
    for (int ww = 0; ww < 8; ++ww) s += red[ww][tid];
    pkq[(size_t)id * NK_ + tid] = s * qmask[b * 32 + q];
  }
}

// ---------------------------------------------------------------------------
// final_k
// ---------------------------------------------------------------------------
__global__ __launch_bounds__(64)
void final_k(const float* __restrict__ pkq, const float* __restrict__ qmask,
             const float* __restrict__ dmask,
             const float* __restrict__ dw, const float* __restrict__ db,
             const float* __restrict__ dmw, const float* __restrict__ dmb,
             const float* __restrict__ cw, float* __restrict__ out)
{
  const int b = blockIdx.x, tid = threadIdx.x;
  float dl = 0.f;
  for (int j = tid; j < 512; j += 64) dl += dmask[b * 512 + j];
  dl = wave_sum(dl);
  dl = __shfl(dl, 0);
  float v1 = 0.f, v2 = 0.f;
  if (tid < 55) {
    const int c = tid / NK_, k = tid % NK_;
    const float rdl = 1.f / dl;
    float s1 = 0.f, s2 = 0.f;
    for (int q = 0; q < 32; ++q) {
      const float p = pkq[(size_t)((b * 5 + c) * 32 + q) * NK_ + k];
      const float qmv = qmask[b * 32 + q];
      s1 += logf(fmaxf(p, 1e-10f)) * qmv;
      s2 += logf(fmaxf(p * rdl, 1e-10f)) * qmv;
    }
    v1 = s1 * dw[tid];
    v2 = s2 * dmw[tid];
  }
  v1 = wave_sum(v1);
  v2 = wave_sum(v2);
  if (tid == 0) out[b] = (v1 + db[0]) * cw[0] + (v2 + dmb[0]) * cw[1];
}

}  // namespace

extern "C" void kernel_launch(void* const* d_in, const int* in_sizes, int n_in,
                              void* d_out, int out_size, void* d_ws, size_t ws_size,
                              hipStream_t stream)
{
  const float* qe  = (const float*)d_in[0];
  const float* de  = (const float*)d_in[1];
  const float* qm  = (const float*)d_in[2];
  const float* dm  = (const float*)d_in[3];
  const float* W1  = (const float*)d_in[6];
  const float* b1  = (const float*)d_in[7];
  const float* W2  = (const float*)d_in[8];
  const float* b2  = (const float*)d_in[9];
  const float* ffg = (const float*)d_in[10];
  const float* ffb = (const float*)d_in[11];
  const float* Wc  = (const float*)d_in[12];
  const float* bc  = (const float*)d_in[13];
  const float* Wo  = (const float*)d_in[14];
  const float* bo  = (const float*)d_in[15];
  const float* lng = (const float*)d_in[16];
  const float* lnb = (const float*)d_in[17];
  const float* c1w = (const float*)d_in[18];
  const float* c1b = (const float*)d_in[19];
  const float* c2w = (const float*)d_in[20];
  const float* c2b = (const float*)d_in[21];
  const float* c3w = (const float*)d_in[22];
  const float* c3b = (const float*)d_in[23];
  const float* c4w = (const float*)d_in[24];
  const float* c4b = (const float*)d_in[25];
  const float* c5w = (const float*)d_in[26];
  const float* c5b = (const float*)d_in[27];
  const float* dwp  = (const float*)d_in[28];
  const float* dbp  = (const float*)d_in[29];
  const float* dmwp = (const float*)d_in[30];
  const float* dmbp = (const float*)d_in[31];
  const float* cwp  = (const float*)d_in[32];

  float* ws = (float*)d_ws;
  size_t off = 0;
  auto alloc = [&](size_t n) { float* p = ws + off; off += n; return p; };
  float* ffq      = alloc((size_t)B_ * TQ_ * E_);
  float* combq    = alloc((size_t)B_ * TQ_ * CD_);
  float* oq       = alloc((size_t)B_ * TQ_ * AD_);
  float* qctx     = alloc((size_t)B_ * TQ_ * E_);
  float* qn       = alloc((size_t)B_ * TQ_ * E_);
  float* ffd      = alloc((size_t)B_ * TD_ * E_);
  float* combd    = alloc((size_t)B_ * TD_ * CD_);
  float* od       = alloc((size_t)B_ * TD_ * AD_);
  float* dctxT    = alloc((size_t)B_ * E_ * TD_);
  float* dnT      = alloc((size_t)B_ * E_ * TD_);
  float* combined = alloc((size_t)B_ * 2 * TQ_ * TD_);
  float* convout  = alloc((size_t)B_ * 5 * TQ_ * TD_);
  float* pkq      = alloc((size_t)B_ * 5 * TQ_ * NK_);

  encode_front_v4<<<DOCBLK_ + 32, 256, 0, stream>>>(
      qe, de, W1, b1, W2, b2, ffg, ffb, Wc, bc,
      ffq, combq, qn, ffd, combd, dnT);
  attn<TQ_><<<B_ * NH_, 64, 0, stream>>>(combq, qm, oq);
  attn<TD_><<<B_ * NH_, 512, 0, stream>>>(combd, dm, od);
  encode_back_v2<<<DOCBLK_ + 32, 256, 0, stream>>>(
      oq, od, ffq, ffd, Wo, bo, lng, lnb, qm, dm, qctx, dctxT);
  simtanh_v2<<<256, 512, 0, stream>>>(qctx, qn, dctxT, dnT, combined);
  conv_all<<<B_ * 32, 512, 0, stream>>>(
      combined, c1w, c1b, c2w, c2b, c3w, c3b, c4w, c4b, c5w, c5b, convout);
  rbf_pkq<<<B_ * 5 * TQ_, 512, 0, stream>>>(convout, dm, qm, pkq);
  final_k<<<B_, 64, 0, stream>>>(pkq, qm, dm, dwp, dbp, dmwp, dmbp, cwp,
                                 (float*)d_out);
}